// Round 1
// baseline (151.032 us; speedup 1.0000x reference)
//
#include <hip/hip_runtime.h>
#include <math.h>

#define BB 16
#define AA 262144
#define GG 128
#define TPB 256
#define APT 4   // anchors per thread

// ws layout: [0..BB)   = per-image l1 sums (float)
//            [BB..2BB) = per-image fg counts (float)

__global__ void zero_ws_kernel(float* __restrict__ p) {
    int t = threadIdx.x;
    if (t < 2 * BB) p[t] = 0.0f;
}

__global__ __launch_bounds__(TPB) void loss_main_kernel(
    const float4* __restrict__ reg,    // [B*A]
    const float4* __restrict__ anc,    // [A]
    const float4* __restrict__ gt,     // [B*G]
    const int4*  __restrict__ mi4,     // [B*A/4]
    float* __restrict__ partial)       // [2*BB]
{
    __shared__ float4 gts[GG];
    __shared__ float red_s[TPB / 64];
    __shared__ float red_c[TPB / 64];

    const int b = blockIdx.y;
    const int t = threadIdx.x;

    // stage this image's gt boxes in LDS (2 KB)
    if (t < GG) gts[t] = gt[b * GG + t];
    __syncthreads();

    const int a0 = blockIdx.x * (TPB * APT) + t * APT;
    const int4 m = mi4[(b * AA) / 4 + blockIdx.x * TPB + t];
    const int mm[4] = { m.x, m.y, m.z, m.w };

    float lsum = 0.0f;
    float lcnt = 0.0f;

#pragma unroll
    for (int j = 0; j < APT; ++j) {
        const int a = a0 + j;
        const float4 an = anc[a];
        const float4 r  = reg[b * AA + a];
        const int mj = mm[j];
        const int mc = mj < 0 ? 0 : mj;
        const float4 g = gts[mc];

        const float ex_w  = an.z - an.x;
        const float ex_h  = an.w - an.y;
        const float ex_cx = an.x + 0.5f * ex_w;
        const float ex_cy = an.y + 0.5f * ex_h;
        const float gt_w  = g.z - g.x;
        const float gt_h  = g.w - g.y;
        const float gt_cx = g.x + 0.5f * gt_w;
        const float gt_cy = g.y + 0.5f * gt_h;

        const float dx = (gt_cx - ex_cx) / ex_w;
        const float dy = (gt_cy - ex_cy) / ex_h;
        const float dw = __logf(gt_w / ex_w);
        const float dh = __logf(gt_h / ex_h);

        const float l1 = fabsf(r.x - dx) + fabsf(r.y - dy) +
                         fabsf(r.z - dw) + fabsf(r.w - dh);
        if (mj >= 0) { lsum += l1; lcnt += 1.0f; }
    }

    // wave-64 shuffle reduction
#pragma unroll
    for (int o = 32; o > 0; o >>= 1) {
        lsum += __shfl_down(lsum, o);
        lcnt += __shfl_down(lcnt, o);
    }
    const int lane = t & 63;
    const int w    = t >> 6;
    if (lane == 0) { red_s[w] = lsum; red_c[w] = lcnt; }
    __syncthreads();

    if (t == 0) {
        float s = 0.0f, c = 0.0f;
#pragma unroll
        for (int i = 0; i < TPB / 64; ++i) { s += red_s[i]; c += red_c[i]; }
        atomicAdd(&partial[b], s);
        atomicAdd(&partial[BB + b], c);
    }
}

__global__ void loss_final_kernel(const float* __restrict__ partial,
                                  float* __restrict__ out)
{
    if (threadIdx.x == 0) {
        float acc = 0.0f;
#pragma unroll
        for (int b = 0; b < BB; ++b) {
            const float c = partial[BB + b];
            acc += partial[b] / fmaxf(1.0f, c);
        }
        out[0] = acc / (float)BB;
    }
}

extern "C" void kernel_launch(void* const* d_in, const int* in_sizes, int n_in,
                              void* d_out, int out_size, void* d_ws, size_t ws_size,
                              hipStream_t stream) {
    const float4* reg = (const float4*)d_in[0];   // bbox_regression [B,A,4]
    const float4* anc = (const float4*)d_in[1];   // anchors [A,4]
    const float4* gt  = (const float4*)d_in[2];   // gt_boxes [B,G,4]
    const int4*   mi  = (const int4*)d_in[3];     // matched_idxs [B,A]

    float* partial = (float*)d_ws;

    zero_ws_kernel<<<1, 64, 0, stream>>>(partial);

    dim3 grid(AA / (TPB * APT), BB);
    loss_main_kernel<<<grid, TPB, 0, stream>>>(reg, anc, gt, mi, partial);

    loss_final_kernel<<<1, 64, 0, stream>>>(partial, (float*)d_out);
}

// Round 2
// 148.837 us; speedup vs baseline: 1.0147x; 1.0147x over previous
//
#include <hip/hip_runtime.h>
#include <math.h>

#define BB 16
#define AA 262144
#define GG 128
#define TPB 256
#define APT 4   // anchors per thread (interleaved at stride TPB for coalescing)

// ws layout: [0..BB)   = per-image l1 sums (float)
//            [BB..2BB) = per-image fg counts (float)

__global__ void zero_ws_kernel(float* __restrict__ p) {
    int t = threadIdx.x;
    if (t < 2 * BB) p[t] = 0.0f;
}

__global__ __launch_bounds__(TPB) void loss_main_kernel(
    const float4* __restrict__ reg,    // [B*A]
    const float4* __restrict__ anc,    // [A]
    const float4* __restrict__ gt,     // [B*G]
    const int*   __restrict__ mi,      // [B*A]
    float* __restrict__ partial)       // [2*BB]
{
    __shared__ float4 gts[GG];
    __shared__ float red_s[TPB / 64];
    __shared__ float red_c[TPB / 64];

    const int b = blockIdx.y;
    const int t = threadIdx.x;

    // stage this image's gt boxes in LDS (2 KB)
    if (t < GG) gts[t] = gt[b * GG + t];
    __syncthreads();

    const int base = blockIdx.x * (TPB * APT);

    // batched, fully-coalesced loads: lane t reads contiguous 16B/4B
    float4 an[APT], r[APT];
    int    mm[APT];
#pragma unroll
    for (int j = 0; j < APT; ++j) {
        const int a = base + j * TPB + t;
        an[j] = anc[a];
        r[j]  = reg[b * AA + a];
        mm[j] = mi[b * AA + a];
    }

    float lsum = 0.0f;
    float lcnt = 0.0f;

#pragma unroll
    for (int j = 0; j < APT; ++j) {
        const int mj = mm[j];
        const int mc = mj < 0 ? 0 : mj;
        const float4 g = gts[mc];

        const float ex_w  = an[j].z - an[j].x;
        const float ex_h  = an[j].w - an[j].y;
        const float ex_cx = an[j].x + 0.5f * ex_w;
        const float ex_cy = an[j].y + 0.5f * ex_h;
        const float gt_w  = g.z - g.x;
        const float gt_h  = g.w - g.y;
        const float gt_cx = g.x + 0.5f * gt_w;
        const float gt_cy = g.y + 0.5f * gt_h;

        const float dx = (gt_cx - ex_cx) / ex_w;
        const float dy = (gt_cy - ex_cy) / ex_h;
        const float dw = __logf(gt_w / ex_w);
        const float dh = __logf(gt_h / ex_h);

        const float l1 = fabsf(r[j].x - dx) + fabsf(r[j].y - dy) +
                         fabsf(r[j].z - dw) + fabsf(r[j].w - dh);
        if (mj >= 0) { lsum += l1; lcnt += 1.0f; }
    }

    // wave-64 shuffle reduction
#pragma unroll
    for (int o = 32; o > 0; o >>= 1) {
        lsum += __shfl_down(lsum, o);
        lcnt += __shfl_down(lcnt, o);
    }
    const int lane = t & 63;
    const int w    = t >> 6;
    if (lane == 0) { red_s[w] = lsum; red_c[w] = lcnt; }
    __syncthreads();

    if (t == 0) {
        float s = 0.0f, c = 0.0f;
#pragma unroll
        for (int i = 0; i < TPB / 64; ++i) { s += red_s[i]; c += red_c[i]; }
        atomicAdd(&partial[b], s);
        atomicAdd(&partial[BB + b], c);
    }
}

__global__ void loss_final_kernel(const float* __restrict__ partial,
                                  float* __restrict__ out)
{
    if (threadIdx.x == 0) {
        float acc = 0.0f;
#pragma unroll
        for (int b = 0; b < BB; ++b) {
            const float c = partial[BB + b];
            acc += partial[b] / fmaxf(1.0f, c);
        }
        out[0] = acc / (float)BB;
    }
}

extern "C" void kernel_launch(void* const* d_in, const int* in_sizes, int n_in,
                              void* d_out, int out_size, void* d_ws, size_t ws_size,
                              hipStream_t stream) {
    const float4* reg = (const float4*)d_in[0];   // bbox_regression [B,A,4]
    const float4* anc = (const float4*)d_in[1];   // anchors [A,4]
    const float4* gt  = (const float4*)d_in[2];   // gt_boxes [B,G,4]
    const int*    mi  = (const int*)d_in[3];      // matched_idxs [B,A]

    float* partial = (float*)d_ws;

    zero_ws_kernel<<<1, 64, 0, stream>>>(partial);

    dim3 grid(AA / (TPB * APT), BB);
    loss_main_kernel<<<grid, TPB, 0, stream>>>(reg, anc, gt, mi, partial);

    loss_final_kernel<<<1, 64, 0, stream>>>(partial, (float*)d_out);
}

// Round 3
// 120.279 us; speedup vs baseline: 1.2557x; 1.2374x over previous
//
#include <hip/hip_runtime.h>
#include <math.h>

#define BB 16
#define AA 262144
#define GG 128
#define TPB 256
#define NBLK (AA / TPB)   // 1024 blocks, 1 anchor per thread

// ws layout (floats):
//   [0 .. BB*NBLK)           per-image per-block l1 sums   (sum[b*NBLK + blk])
//   [BB*NBLK .. 2*BB*NBLK)   per-image per-block fg counts
//   [2*BB*NBLK .. +BB)       per-image normalized losses

__global__ __launch_bounds__(TPB, 4) void loss_main_kernel(
    const float4* __restrict__ reg,    // [B*A]
    const float4* __restrict__ anc,    // [A]
    const float4* __restrict__ gt,     // [B*G]
    const int*   __restrict__ mi,      // [B*A]
    float* __restrict__ ws_sum,        // [BB*NBLK]
    float* __restrict__ ws_cnt)        // [BB*NBLK]
{
    __shared__ float4 gts[BB * GG];    // 32 KB: (cx, cy, log w, log h)
    __shared__ float redS[BB * 4];
    __shared__ float redC[BB * 4];

    const int t  = threadIdx.x;
    const int bx = blockIdx.x;

    // stage ALL images' gt boxes, pre-transformed (done once per block)
#pragma unroll
    for (int i = 0; i < (BB * GG) / TPB; ++i) {
        const float4 g = gt[i * TPB + t];
        const float w = g.z - g.x;
        const float h = g.w - g.y;
        gts[i * TPB + t] = make_float4(g.x + 0.5f * w, g.y + 0.5f * h,
                                       __logf(w), __logf(h));
    }
    __syncthreads();

    // per-anchor invariants (hoisted out of the b-loop)
    const int a = bx * TPB + t;
    const float4 an = anc[a];
    const float ex_w  = an.z - an.x;
    const float ex_h  = an.w - an.y;
    const float ex_cx = an.x + 0.5f * ex_w;
    const float ex_cy = an.y + 0.5f * ex_h;
    const float inv_w = 1.0f / ex_w;
    const float inv_h = 1.0f / ex_h;
    const float lw    = __logf(ex_w);
    const float lh    = __logf(ex_h);

    const int wv   = t >> 6;
    const int lane = t & 63;

#pragma unroll
    for (int b = 0; b < BB; ++b) {
        const int    mj = mi[b * AA + a];
        const float4 r  = reg[b * AA + a];
        const float4 g  = gts[b * GG + (mj < 0 ? 0 : mj)];

        const float dx = (g.x - ex_cx) * inv_w;
        const float dy = (g.y - ex_cy) * inv_h;
        const float dw = g.z - lw;
        const float dh = g.w - lh;

        const float l1 = fabsf(r.x - dx) + fabsf(r.y - dy) +
                         fabsf(r.z - dw) + fabsf(r.w - dh);
        float s = (mj >= 0) ? l1 : 0.0f;
        float c = (mj >= 0) ? 1.0f : 0.0f;

        // wave-64 reduction
#pragma unroll
        for (int o = 32; o > 0; o >>= 1) {
            s += __shfl_down(s, o);
            c += __shfl_down(c, o);
        }
        if (lane == 0) { redS[b * 4 + wv] = s; redC[b * 4 + wv] = c; }
    }
    __syncthreads();

    if (t < BB) {
        const float s = redS[t * 4] + redS[t * 4 + 1] +
                        redS[t * 4 + 2] + redS[t * 4 + 3];
        const float c = redC[t * 4] + redC[t * 4 + 1] +
                        redC[t * 4 + 2] + redC[t * 4 + 3];
        ws_sum[t * NBLK + bx] = s;
        ws_cnt[t * NBLK + bx] = c;
    }
}

// one block per image: reduce NBLK partials -> per_img[b] = s / max(1, c)
__global__ __launch_bounds__(TPB) void reduce_image_kernel(
    const float* __restrict__ ws_sum,
    const float* __restrict__ ws_cnt,
    float* __restrict__ per_img)
{
    __shared__ float redS[TPB / 64];
    __shared__ float redC[TPB / 64];
    const int b = blockIdx.x;
    const int t = threadIdx.x;

    float s = 0.0f, c = 0.0f;
    for (int i = t; i < NBLK; i += TPB) {
        s += ws_sum[b * NBLK + i];
        c += ws_cnt[b * NBLK + i];
    }
#pragma unroll
    for (int o = 32; o > 0; o >>= 1) {
        s += __shfl_down(s, o);
        c += __shfl_down(c, o);
    }
    const int lane = t & 63, wv = t >> 6;
    if (lane == 0) { redS[wv] = s; redC[wv] = c; }
    __syncthreads();
    if (t == 0) {
        float ss = 0.0f, cc = 0.0f;
#pragma unroll
        for (int i = 0; i < TPB / 64; ++i) { ss += redS[i]; cc += redC[i]; }
        per_img[b] = ss / fmaxf(1.0f, cc);
    }
}

__global__ void final_kernel(const float* __restrict__ per_img,
                             float* __restrict__ out)
{
    if (threadIdx.x == 0) {
        float acc = 0.0f;
#pragma unroll
        for (int b = 0; b < BB; ++b) acc += per_img[b];
        out[0] = acc / (float)BB;
    }
}

extern "C" void kernel_launch(void* const* d_in, const int* in_sizes, int n_in,
                              void* d_out, int out_size, void* d_ws, size_t ws_size,
                              hipStream_t stream) {
    const float4* reg = (const float4*)d_in[0];   // bbox_regression [B,A,4]
    const float4* anc = (const float4*)d_in[1];   // anchors [A,4]
    const float4* gt  = (const float4*)d_in[2];   // gt_boxes [B,G,4]
    const int*    mi  = (const int*)d_in[3];      // matched_idxs [B,A]

    float* ws_sum  = (float*)d_ws;
    float* ws_cnt  = ws_sum + BB * NBLK;
    float* per_img = ws_cnt + BB * NBLK;

    loss_main_kernel<<<NBLK, TPB, 0, stream>>>(reg, anc, gt, mi, ws_sum, ws_cnt);
    reduce_image_kernel<<<BB, TPB, 0, stream>>>(ws_sum, ws_cnt, per_img);
    final_kernel<<<1, 64, 0, stream>>>(per_img, (float*)d_out);
}

// Round 4
// 110.391 us; speedup vs baseline: 1.3682x; 1.0896x over previous
//
#include <hip/hip_runtime.h>
#include <math.h>

#define BB 16
#define AA 262144
#define GG 128
#define TPB 256
#define NBLK (AA / TPB)   // 1024 blocks, 1 anchor per thread

// ws layout (floats):
//   [0 .. BB*NBLK)           per-image per-block l1 sums   (sum[b*NBLK + blk])
//   [BB*NBLK .. 2*BB*NBLK)   per-image per-block fg counts

__global__ __launch_bounds__(TPB, 4) void loss_main_kernel(
    const float4* __restrict__ reg,    // [B*A]
    const float4* __restrict__ anc,    // [A]
    const float4* __restrict__ gt,     // [B*G]
    const int*   __restrict__ mi,      // [B*A]
    float* __restrict__ ws_sum,        // [BB*NBLK]
    float* __restrict__ ws_cnt)        // [BB*NBLK]
{
    __shared__ float4 gts[BB * GG];    // 32 KB: (cx, cy, log w, log h)
    __shared__ float redS[BB * 4];
    __shared__ float redC[BB * 4];

    const int t  = threadIdx.x;
    const int bx = blockIdx.x;

    // stage ALL images' gt boxes, pre-transformed (once per block)
#pragma unroll
    for (int i = 0; i < (BB * GG) / TPB; ++i) {
        const float4 g = gt[i * TPB + t];
        const float w = g.z - g.x;
        const float h = g.w - g.y;
        gts[i * TPB + t] = make_float4(g.x + 0.5f * w, g.y + 0.5f * h,
                                       __logf(w), __logf(h));
    }

    // per-anchor invariants (independent of LDS -> overlaps staging)
    const int a = bx * TPB + t;
    const float4 an = anc[a];
    const float ex_w  = an.z - an.x;
    const float ex_h  = an.w - an.y;
    const float ex_cx = an.x + 0.5f * ex_w;
    const float ex_cy = an.y + 0.5f * ex_h;
    const float inv_w = 1.0f / ex_w;
    const float inv_h = 1.0f / ex_h;
    const float lw    = __logf(ex_w);
    const float lh    = __logf(ex_h);

    // prefetch ALL matched indices (16 outstanding scalar loads)
    int mjv[BB];
#pragma unroll
    for (int b = 0; b < BB; ++b) mjv[b] = mi[b * AA + a];

    __syncthreads();   // gts ready

    const int wv   = t >> 6;
    const int lane = t & 63;

    // two half-batches: prefetch 8 float4 regs, then compute those 8
#pragma unroll
    for (int half = 0; half < 2; ++half) {
        float4 r[8];
#pragma unroll
        for (int j = 0; j < 8; ++j)
            r[j] = reg[(half * 8 + j) * AA + a];

#pragma unroll
        for (int j = 0; j < 8; ++j) {
            const int b  = half * 8 + j;
            const int mj = mjv[b];
            const float4 g = gts[b * GG + (mj < 0 ? 0 : mj)];

            const float dx = (g.x - ex_cx) * inv_w;
            const float dy = (g.y - ex_cy) * inv_h;
            const float dw = g.z - lw;
            const float dh = g.w - lh;

            const float l1 = fabsf(r[j].x - dx) + fabsf(r[j].y - dy) +
                             fabsf(r[j].z - dw) + fabsf(r[j].w - dh);
            float s = (mj >= 0) ? l1 : 0.0f;

            // sum via shuffle; count via ballot+popcount
            const unsigned long long bal = __ballot(mj >= 0);
#pragma unroll
            for (int o = 32; o > 0; o >>= 1) s += __shfl_down(s, o);

            if (lane == 0) {
                redS[b * 4 + wv] = s;
                redC[b * 4 + wv] = (float)__popcll(bal);
            }
        }
    }
    __syncthreads();

    if (t < BB) {
        const float s = redS[t * 4] + redS[t * 4 + 1] +
                        redS[t * 4 + 2] + redS[t * 4 + 3];
        const float c = redC[t * 4] + redC[t * 4 + 1] +
                        redC[t * 4 + 2] + redC[t * 4 + 3];
        ws_sum[t * NBLK + bx] = s;
        ws_cnt[t * NBLK + bx] = c;
    }
}

// single block: each wave reduces 4 images, thread 0 combines
__global__ __launch_bounds__(TPB) void reduce_final_kernel(
    const float* __restrict__ ws_sum,
    const float* __restrict__ ws_cnt,
    float* __restrict__ out)
{
    __shared__ float per_img[BB];
    const int t    = threadIdx.x;
    const int wv   = t >> 6;
    const int lane = t & 63;

#pragma unroll
    for (int k = 0; k < 4; ++k) {
        const int b = wv * 4 + k;
        float s = 0.0f, c = 0.0f;
#pragma unroll
        for (int i = 0; i < NBLK / 64; ++i) {
            s += ws_sum[b * NBLK + i * 64 + lane];
            c += ws_cnt[b * NBLK + i * 64 + lane];
        }
#pragma unroll
        for (int o = 32; o > 0; o >>= 1) {
            s += __shfl_down(s, o);
            c += __shfl_down(c, o);
        }
        if (lane == 0) per_img[b] = s / fmaxf(1.0f, c);
    }
    __syncthreads();

    if (t == 0) {
        float acc = 0.0f;
#pragma unroll
        for (int b = 0; b < BB; ++b) acc += per_img[b];
        out[0] = acc / (float)BB;
    }
}

extern "C" void kernel_launch(void* const* d_in, const int* in_sizes, int n_in,
                              void* d_out, int out_size, void* d_ws, size_t ws_size,
                              hipStream_t stream) {
    const float4* reg = (const float4*)d_in[0];   // bbox_regression [B,A,4]
    const float4* anc = (const float4*)d_in[1];   // anchors [A,4]
    const float4* gt  = (const float4*)d_in[2];   // gt_boxes [B,G,4]
    const int*    mi  = (const int*)d_in[3];      // matched_idxs [B,A]

    float* ws_sum = (float*)d_ws;
    float* ws_cnt = ws_sum + BB * NBLK;

    loss_main_kernel<<<NBLK, TPB, 0, stream>>>(reg, anc, gt, mi, ws_sum, ws_cnt);
    reduce_final_kernel<<<1, TPB, 0, stream>>>(ws_sum, ws_cnt, (float*)d_out);
}